// Round 1
// baseline (221.490 us; speedup 1.0000x reference)
//
#include <hip/hip_runtime.h>

#define M_DIM   96
#define IN_DIM  16
#define OUT_DIM 16
#define N_BATCH 4
#define PLANE4  (M_DIM * M_DIM / 4)    // 2304 float4 per (j,k) plane
#define PPB     3                      // planes (i values) per block

typedef float f4 __attribute__((ext_vector_type(4)));

// out[n,s,i,j,k] = Y0[n,s,i] + Y1[n,s,j] + Y2[n,s,k] + S[n,s] + bias[s]
//
// R2 structure: 226.5 MB pure-write kernel; fill dispatches prove 6.6 TB/s is
// achievable on this buffer, we were at ~2.7 TB/s. Changes vs R1-best:
//  - 3 consecutive i-planes per block, same (n,s): grid 2048 = 8 blocks/CU x
//    256 CUs -> single resident round, setup amortized 3x. (R1's regression
//    was NT stores + cross-ns 4-chunking; neither is used here.)
//  - ONE barrier: all-wave butterfly reduction of s_red via __shfl_xor, every
//    lane gets S; no s_S round-trip, no second __syncthreads.
//  - store loop stripped to add+store: per-(t,it) y1[j]+y2[k] hoisted into
//    9 float4 registers before the plane loop (the (t,it)->(j,kq) map is
//    plane-invariant), so no LDS reads / no div-by-24 inside the hot loop.
__global__ __launch_bounds__(256) void eq13_kernel(
    const float* __restrict__ x,      // (N, IN_DIM, M)
    const float* __restrict__ coefs,  // (IN_DIM, OUT_DIM, 4)
    const float* __restrict__ bias,   // (OUT_DIM)
    f4* __restrict__ out4)            // (N, OUT_DIM, M, M, M) as float4
{
    __shared__ float s_y0[M_DIM];
    __shared__ float s_y1[M_DIM];
    __shared__ __align__(16) float s_y2[M_DIM];
    __shared__ float s_red[M_DIM];

    const int bid = blockIdx.x;          // 0 .. 2047
    const int ns  = bid >> 5;            // n*16 + s   (0..63)
    const int ig  = (bid & 31) * PPB;    // first i-plane: 0,3,...,93
    const int n   = ns >> 4;
    const int s   = ns & 15;
    const int t   = threadIdx.x;

    const float bs = bias[s];            // uniform, hoisted above the barrier

    if (t < M_DIM) {
        float y0 = 0.f, y1 = 0.f, y2 = 0.f, y3 = 0.f;
        const float* xb = x + (size_t)n * IN_DIM * M_DIM + t;   // coalesced over t
        const float* cb = coefs + s * 4;
        #pragma unroll
        for (int d = 0; d < IN_DIM; ++d) {
            float xv = xb[d * M_DIM];
            f4 c4 = *(const f4*)(cb + d * OUT_DIM * 4);  // c[d][s][0..3]
            y0 = fmaf(xv, c4.x, y0);
            y1 = fmaf(xv, c4.y, y1);
            y2 = fmaf(xv, c4.z, y2);
            y3 = fmaf(xv, c4.w, y3);
        }
        s_y0[t]  = y0;
        s_y1[t]  = y1;
        s_y2[t]  = y2;
        s_red[t] = y3;
    }
    __syncthreads();   // the only barrier

    // All-wave butterfly reduction of s_red[0..95]: every lane ends with S.
    {
        const int lane = t & 63;
        float v = s_red[lane] + ((lane < 32) ? s_red[lane + 64] : 0.f);
        #pragma unroll
        for (int off = 32; off; off >>= 1) v += __shfl_xor(v, off);
        s_red[0] = s_red[0];  // no-op; keep LDS live region obvious
        // fallthrough: v == sum over all 96 entries
        const float S = v + bs;

        // Hoist per-(t,it) y1[j] + y2[4k..4k+3] into registers (plane-invariant).
        const f4* y2v = (const f4*)s_y2;                 // 24 x float4
        f4 g[9];
        #pragma unroll
        for (int it = 0; it < 9; ++it) {
            int   c  = t + it * 256;      // 0 .. 2303
            int   j  = c / 24;            // row (0..95)
            int   kq = c - j * 24;        // float4 idx along k
            float w  = s_y1[j];
            f4    f  = y2v[kq];
            f.x += w; f.y += w; f.z += w; f.w += w;
            g[it] = f;
        }

        // 3 planes x 2304 float4; inner loop is pure add+store, fully coalesced.
        f4* dst = out4 + (size_t)(ns * M_DIM + ig) * PLANE4;
        #pragma unroll
        for (int p = 0; p < PPB; ++p) {
            const float base = s_y0[ig + p] + S;
            #pragma unroll
            for (int it = 0; it < 9; ++it) {
                f4 f = g[it];
                f.x += base; f.y += base; f.z += base; f.w += base;
                dst[p * PLANE4 + t + it * 256] = f;
            }
        }
    }
}

extern "C" void kernel_launch(void* const* d_in, const int* in_sizes, int n_in,
                              void* d_out, int out_size, void* d_ws, size_t ws_size,
                              hipStream_t stream) {
    const float* x     = (const float*)d_in[0];
    const float* coefs = (const float*)d_in[1];
    const float* bias  = (const float*)d_in[2];
    f4* out4 = (f4*)d_out;

    const int grid = N_BATCH * OUT_DIM * (M_DIM / PPB);   // 2048 blocks
    eq13_kernel<<<grid, 256, 0, stream>>>(x, coefs, bias, out4);
}